// Round 1
// baseline (168.322 us; speedup 1.0000x reference)
//
#include <hip/hip_runtime.h>

#define NP   4096      // P = 64*64 pixels per image
#define NIMG 8
#define NK   21
#define ROWF 32        // floats per packed row: [0..4]=scaled feat, [5..7]=0, [8..28]=seg, [29..31]=0
#define JCHUNK 512

// sqrt(0.5 * log2(e)): pre-scale features so exponent = -sum((fi-fj)^2), w = exp2(exponent)
#define FEAT_SCALE 0.84932180028801907f

__device__ __forceinline__ void resize_w(int o, float* w, int* t) {
  // jax.image.resize bilinear antialias=True, 128->64: taps 2o-1..2o+2, base weights
  // (0.25,0.75,0.75,0.25), renormalized over valid taps.
  const float ww[4] = {0.25f, 0.75f, 0.75f, 0.25f};
  float s = 0.f;
  #pragma unroll
  for (int a = 0; a < 4; ++a) {
    int tap = 2 * o - 1 + a;
    bool v = (tap >= 0) && (tap < 128);
    w[a] = v ? ww[a] : 0.f;
    t[a] = v ? tap : 0;
    s += w[a];
  }
  float inv = 1.f / s;
  #pragma unroll
  for (int a = 0; a < 4; ++a) w[a] *= inv;
}

__global__ void prep_kernel(const float* __restrict__ images,
                            const float* __restrict__ segs,
                            float* __restrict__ rows) {
  int idx = blockIdx.x * blockDim.x + threadIdx.x;   // n*NP + p
  if (idx >= NIMG * NP) return;
  int n = idx >> 12;
  int p = idx & (NP - 1);
  int ox = p & 63, oy = p >> 6;
  float* row = rows + (size_t)idx * ROWF;

  const float cxy  = FEAT_SCALE / 50.0f;   // sigma_xy * scale = 50
  const float crgb = FEAT_SCALE / 15.0f;   // sigma_rgb = 15
  const float* img = images + (size_t)n * 3 * NP;
  row[0] = (float)ox * cxy;
  row[1] = (float)oy * cxy;
  row[2] = img[0 * NP + p] * crgb;
  row[3] = img[1 * NP + p] * crgb;
  row[4] = img[2 * NP + p] * crgb;
  row[5] = 0.f; row[6] = 0.f; row[7] = 0.f;

  float wy[4], wx[4]; int ty[4], tx[4];
  resize_w(oy, wy, ty);
  resize_w(ox, wx, tx);
  const float* sb = segs + (size_t)n * NK * 128 * 128;
  #pragma unroll 1
  for (int k = 0; k < NK; ++k) {
    const float* sk = sb + (size_t)k * 128 * 128;
    float a = 0.f;
    #pragma unroll
    for (int ay = 0; ay < 4; ++ay) {
      const float* srow = sk + ty[ay] * 128;
      float rsum = 0.f;
      #pragma unroll
      for (int ax = 0; ax < 4; ++ax) rsum = fmaf(wx[ax], srow[tx[ax]], rsum);
      a = fmaf(wy[ay], rsum, a);
    }
    row[8 + k] = a;
  }
  row[29] = 0.f; row[30] = 0.f; row[31] = 0.f;
}

__global__ void __launch_bounds__(256) crf_kernel(const float* __restrict__ rows,
                                                  double* __restrict__ acc) {
  int bid = blockIdx.x;           // grid = NIMG * (NP/256) * (NP/JCHUNK) = 8*16*8
  int jb = bid & 7;
  int it = (bid >> 3) & 15;
  int n  = bid >> 7;
  int i  = it * 256 + threadIdx.x;

  const float* base = rows + (size_t)n * NP * ROWF;
  float ai[ROWF];
  {
    const float4* src = (const float4*)(base + (size_t)i * ROWF);
    #pragma unroll
    for (int q = 0; q < 8; ++q) {
      float4 v = src[q];
      ai[4*q+0] = v.x; ai[4*q+1] = v.y; ai[4*q+2] = v.z; ai[4*q+3] = v.w;
    }
  }

  float sum = 0.f;
  const float* jrow = base + (size_t)jb * JCHUNK * ROWF;
  #pragma unroll 1
  for (int jj = 0; jj < JCHUNK; ++jj, jrow += ROWF) {
    float bj[ROWF];
    #pragma unroll
    for (int q = 0; q < 8; ++q) {
      float4 v = ((const float4*)jrow)[q];
      bj[4*q+0] = v.x; bj[4*q+1] = v.y; bj[4*q+2] = v.z; bj[4*q+3] = v.w;
    }
    float t = 0.f;
    #pragma unroll
    for (int q = 0; q < 5; ++q) { float d = ai[q] - bj[q]; t = fmaf(d, d, t); }
    float w = __builtin_amdgcn_exp2f(-t);
    float g = 0.f;
    #pragma unroll
    for (int q = 8; q < 29; ++q) g = fmaf(ai[q], bj[q], g);
    sum = fmaf(w, g, sum);
  }

  // block reduction: wave shuffle then cross-wave via LDS
  #pragma unroll
  for (int off = 32; off > 0; off >>= 1) sum += __shfl_down(sum, off);
  __shared__ float red[4];
  int lane = threadIdx.x & 63, wid = threadIdx.x >> 6;
  if (lane == 0) red[wid] = sum;
  __syncthreads();
  if (threadIdx.x == 0) {
    float b = red[0] + red[1] + red[2] + red[3];
    atomicAdd(acc, (double)b);
  }
}

__global__ void finish_kernel(const double* __restrict__ acc, float* __restrict__ out) {
  // loss = -sum/N ; out = WEIGHT * loss = -1e-8/8 * sum
  out[0] = (float)(acc[0] * (-1e-8 / 8.0));
}

extern "C" void kernel_launch(void* const* d_in, const int* in_sizes, int n_in,
                              void* d_out, int out_size, void* d_ws, size_t ws_size,
                              hipStream_t stream) {
  const float* images = (const float*)d_in[0];   // [8,3,64,64]
  const float* segs   = (const float*)d_in[1];   // [8,21,128,128]
  float* out  = (float*)d_out;
  double* acc = (double*)d_ws;
  float* rows = (float*)((char*)d_ws + 256);     // 8*4096*32 floats = 4 MB

  hipMemsetAsync(d_ws, 0, 256, stream);          // zero the accumulator every call
  hipLaunchKernelGGL(prep_kernel, dim3((NIMG * NP + 255) / 256), dim3(256), 0, stream,
                     images, segs, rows);
  hipLaunchKernelGGL(crf_kernel, dim3(NIMG * (NP / 256) * (NP / JCHUNK)), dim3(256), 0, stream,
                     rows, acc);
  hipLaunchKernelGGL(finish_kernel, dim3(1), dim3(1), 0, stream, acc, out);
}

// Round 2
// 100.517 us; speedup vs baseline: 1.6746x; 1.6746x over previous
//
#include <hip/hip_runtime.h>

#define NP   4096      // P = 64*64 pixels per image
#define NIMG 8
#define NK   21
#define ROWH 32        // halves per packed row (64 B)

// sqrt(0.5 * log2(e)): pre-scale features so exponent = -sum((fi-fj)^2), w = exp2(exponent)
#define FEAT_SCALE 0.84932180028801907f

typedef _Float16 half8 __attribute__((ext_vector_type(8)));
typedef float f32x4 __attribute__((ext_vector_type(4)));

__device__ __forceinline__ void resize_w(int o, float* w, int* t) {
  // jax.image.resize bilinear antialias=True, 128->64: taps 2o-1..2o+2, weights
  // (0.25,0.75,0.75,0.25) renormalized over valid taps.
  const float ww[4] = {0.25f, 0.75f, 0.75f, 0.25f};
  float s = 0.f;
  #pragma unroll
  for (int a = 0; a < 4; ++a) {
    int tap = 2 * o - 1 + a;
    bool v = (tap >= 0) && (tap < 128);
    w[a] = v ? ww[a] : 0.f;
    t[a] = v ? tap : 0;
    s += w[a];
  }
  float inv = 1.f / s;
  #pragma unroll
  for (int a = 0; a < 4; ++a) w[a] *= inv;
}

__global__ void prep_kernel(const float* __restrict__ images,
                            const float* __restrict__ segs,
                            _Float16* __restrict__ distA,
                            _Float16* __restrict__ distB,
                            _Float16* __restrict__ segh) {
  int idx = blockIdx.x * blockDim.x + threadIdx.x;   // n*NP + p
  if (idx >= NIMG * NP) return;
  int n = idx >> 12;
  int p = idx & (NP - 1);
  int ox = p & 63, oy = p >> 6;

  const float cxy  = FEAT_SCALE / 50.0f;   // sigma_xy * scale = 50
  const float crgb = FEAT_SCALE / 15.0f;   // sigma_rgb = 15
  const float* img = images + (size_t)n * 3 * NP;
  float f[5];
  f[0] = (float)ox * cxy;
  f[1] = (float)oy * cxy;
  f[2] = img[0 * NP + p] * crgb;
  f[3] = img[1 * NP + p] * crgb;
  f[4] = img[2 * NP + p] * crgb;

  _Float16 ah[5], al[5];
  float n2 = 0.f;
  #pragma unroll
  for (int d = 0; d < 5; ++d) {
    ah[d] = (_Float16)f[d];
    float rem = f[d] - (float)ah[d];
    al[d] = (_Float16)rem;
    float at = (float)ah[d] + (float)al[d];
    n2 = fmaf(at, at, n2);
  }
  _Float16 nh = (_Float16)n2;
  _Float16 nl = (_Float16)(n2 - (float)nh);

  _Float16 rowA[ROWH], rowB[ROWH];
  #pragma unroll
  for (int q = 0; q < ROWH; ++q) { rowA[q] = (_Float16)0.f; rowB[q] = (_Float16)0.f; }
  #pragma unroll
  for (int d = 0; d < 5; ++d) {
    rowA[d]      = ah[d];
    rowA[5 + d]  = al[d];
    rowA[10 + d] = ah[d];
    rowB[d]      = (_Float16)2.f * ah[d];
    rowB[5 + d]  = (_Float16)2.f * ah[d];
    rowB[10 + d] = (_Float16)2.f * al[d];
  }
  rowA[15] = nh;  rowA[16] = nl;  rowA[17] = (_Float16)1.f; rowA[18] = (_Float16)1.f;
  rowB[15] = (_Float16)-1.f; rowB[16] = (_Float16)-1.f; rowB[17] = -nh; rowB[18] = -nl;

  // seg resize (identical arithmetic to the verified fp32 round-1 kernel)
  float wy[4], wx[4]; int ty[4], tx[4];
  resize_w(oy, wy, ty);
  resize_w(ox, wx, tx);
  _Float16 rowS[ROWH];
  #pragma unroll
  for (int q = NK; q < ROWH; ++q) rowS[q] = (_Float16)0.f;
  const float* sb = segs + (size_t)n * NK * 128 * 128;
  #pragma unroll 1
  for (int k = 0; k < NK; ++k) {
    const float* sk = sb + (size_t)k * 128 * 128;
    float a = 0.f;
    #pragma unroll
    for (int ay = 0; ay < 4; ++ay) {
      const float* srow = sk + ty[ay] * 128;
      float rsum = 0.f;
      #pragma unroll
      for (int ax = 0; ax < 4; ++ax) rsum = fmaf(wx[ax], srow[tx[ax]], rsum);
      a = fmaf(wy[ay], rsum, a);
    }
    rowS[k] = (_Float16)a;
  }

  half8* oA = (half8*)(distA + (size_t)idx * ROWH);
  half8* oB = (half8*)(distB + (size_t)idx * ROWH);
  half8* oS = (half8*)(segh  + (size_t)idx * ROWH);
  #pragma unroll
  for (int q = 0; q < 4; ++q) {
    oA[q] = ((half8*)rowA)[q];
    oB[q] = ((half8*)rowB)[q];
    oS[q] = ((half8*)rowS)[q];
  }
}

__global__ void __launch_bounds__(256) crf_mfma(const _Float16* __restrict__ distA,
                                                const _Float16* __restrict__ distB,
                                                const _Float16* __restrict__ segh,
                                                double* __restrict__ acc) {
  int lane = threadIdx.x & 63, wid = threadIdx.x >> 6;
  int gw = blockIdx.x * 4 + wid;          // 0..4095
  int itile = gw >> 1;                    // 0..2047 = n*256 + it
  int n  = itile >> 8;
  int i0 = (itile & 255) * 16;
  int jhalf = gw & 1;                     // each wave: 128 of the 256 j-tiles

  const _Float16* dA = distA + (size_t)n * NP * ROWH;
  const _Float16* dB = distB + (size_t)n * NP * ROWH;
  const _Float16* sg = segh  + (size_t)n * NP * ROWH;

  int r = lane & 15, g4 = lane >> 4;      // fragment row(col) and k-group
  size_t aoff = (size_t)(i0 + r) * ROWH + g4 * 8;
  half8 Ad = *(const half8*)(dA + aoff);
  half8 As = *(const half8*)(sg + aoff);

  size_t boff = (size_t)(jhalf * 2048 + r) * ROWH + g4 * 8;
  const _Float16* pBd = dB + boff;
  const _Float16* pBs = sg + boff;

  float sum = 0.f;
  f32x4 zero = {0.f, 0.f, 0.f, 0.f};
  #pragma unroll 2
  for (int jt = 0; jt < 128; ++jt) {
    half8 Bd = *(const half8*)pBd;
    half8 Bs = *(const half8*)pBs;
    pBd += 16 * ROWH;
    pBs += 16 * ROWH;
    f32x4 accd = __builtin_amdgcn_mfma_f32_16x16x32_f16(Ad, Bd, zero, 0, 0, 0);
    f32x4 accs = __builtin_amdgcn_mfma_f32_16x16x32_f16(As, Bs, zero, 0, 0, 0);
    #pragma unroll
    for (int q = 0; q < 4; ++q)
      sum = fmaf(__builtin_amdgcn_exp2f(accd[q]), accs[q], sum);
  }

  // block reduction: wave shuffle then cross-wave via LDS
  #pragma unroll
  for (int off = 32; off > 0; off >>= 1) sum += __shfl_down(sum, off);
  __shared__ float red[4];
  if ((threadIdx.x & 63) == 0) red[wid] = sum;
  __syncthreads();
  if (threadIdx.x == 0) {
    float b = red[0] + red[1] + red[2] + red[3];
    atomicAdd(acc, (double)b);
  }
}

__global__ void finish_kernel(const double* __restrict__ acc, float* __restrict__ out) {
  // loss = -sum/N ; out = WEIGHT * loss = -1e-8/8 * sum
  out[0] = (float)(acc[0] * (-1e-8 / 8.0));
}

extern "C" void kernel_launch(void* const* d_in, const int* in_sizes, int n_in,
                              void* d_out, int out_size, void* d_ws, size_t ws_size,
                              hipStream_t stream) {
  const float* images = (const float*)d_in[0];   // [8,3,64,64]
  const float* segs   = (const float*)d_in[1];   // [8,21,128,128]
  float* out  = (float*)d_out;
  double* acc = (double*)d_ws;
  _Float16* distA = (_Float16*)((char*)d_ws + 256);              // 2 MB
  _Float16* distB = distA + (size_t)NIMG * NP * ROWH;            // 2 MB
  _Float16* segh  = distB + (size_t)NIMG * NP * ROWH;            // 2 MB

  hipMemsetAsync(d_ws, 0, 256, stream);          // zero the accumulator every call
  hipLaunchKernelGGL(prep_kernel, dim3((NIMG * NP + 255) / 256), dim3(256), 0, stream,
                     images, segs, distA, distB, segh);
  hipLaunchKernelGGL(crf_mfma, dim3(NIMG * 256 * 2 / 4), dim3(256), 0, stream,
                     distA, distB, segh, acc);
  hipLaunchKernelGGL(finish_kernel, dim3(1), dim3(1), 0, stream, acc, out);
}

// Round 3
// 53.312 us; speedup vs baseline: 3.1573x; 1.8854x over previous
//
#include <hip/hip_runtime.h>

#define NP   4096      // P = 64*64 pixels per image
#define NIMG 8
#define NK   21
#define ROWH 32        // halves per packed row (64 B)
#define ITEMS_PER_IMG 544   // sum over supertiles ist of (16 - ist/4) j-chunks

// sqrt(0.5 * log2(e)): pre-scale features so exponent = -sum((fi-fj)^2), w = exp2(exponent)
#define FEAT_SCALE 0.84932180028801907f

typedef _Float16 half8 __attribute__((ext_vector_type(8)));
typedef float f32x4 __attribute__((ext_vector_type(4)));

__device__ __forceinline__ void resize_w(int o, float* w, int* t) {
  // jax.image.resize bilinear antialias=True, 128->64: taps 2o-1..2o+2, weights
  // (0.25,0.75,0.75,0.25) renormalized over valid taps. (verified exact rounds 1-2)
  const float ww[4] = {0.25f, 0.75f, 0.75f, 0.25f};
  float s = 0.f;
  #pragma unroll
  for (int a = 0; a < 4; ++a) {
    int tap = 2 * o - 1 + a;
    bool v = (tap >= 0) && (tap < 128);
    w[a] = v ? ww[a] : 0.f;
    t[a] = v ? tap : 0;
    s += w[a];
  }
  float inv = 1.f / s;
  #pragma unroll
  for (int a = 0; a < 4; ++a) w[a] *= inv;
}

// 128 blocks = (n, oy-group of 4 output rows), 256 threads = 64 ox * 4 oyl.
// Seg slab (10 input rows x 128) staged in LDS with coalesced loads.
__global__ void __launch_bounds__(256) prep_kernel(const float* __restrict__ images,
                                                   const float* __restrict__ segs,
                                                   _Float16* __restrict__ distA,
                                                   _Float16* __restrict__ distB,
                                                   _Float16* __restrict__ segh) {
  int bid = blockIdx.x;
  int n = bid >> 4, oyg = bid & 15;
  int ox = threadIdx.x & 63, oyl = threadIdx.x >> 6;
  int oy = oyg * 4 + oyl;
  int p = oy * 64 + ox;
  int idx = n * NP + p;

  // ---- bilateral features -> distA/distB rows (identical math to verified round 2) ----
  {
    const float cxy  = FEAT_SCALE / 50.0f;   // sigma_xy * scale = 50
    const float crgb = FEAT_SCALE / 15.0f;   // sigma_rgb = 15
    const float* img = images + (size_t)n * 3 * NP;
    float f[5];
    f[0] = (float)ox * cxy;
    f[1] = (float)oy * cxy;
    f[2] = img[0 * NP + p] * crgb;
    f[3] = img[1 * NP + p] * crgb;
    f[4] = img[2 * NP + p] * crgb;

    _Float16 ah[5], al[5];
    float n2 = 0.f;
    #pragma unroll
    for (int d = 0; d < 5; ++d) {
      ah[d] = (_Float16)f[d];
      float rem = f[d] - (float)ah[d];
      al[d] = (_Float16)rem;
      float at = (float)ah[d] + (float)al[d];
      n2 = fmaf(at, at, n2);
    }
    _Float16 nh = (_Float16)n2;
    _Float16 nl = (_Float16)(n2 - (float)nh);

    _Float16 rowA[ROWH], rowB[ROWH];
    #pragma unroll
    for (int q = 0; q < ROWH; ++q) { rowA[q] = (_Float16)0.f; rowB[q] = (_Float16)0.f; }
    #pragma unroll
    for (int d = 0; d < 5; ++d) {
      rowA[d]      = ah[d];
      rowA[5 + d]  = al[d];
      rowA[10 + d] = ah[d];
      rowB[d]      = (_Float16)2.f * ah[d];
      rowB[5 + d]  = (_Float16)2.f * ah[d];
      rowB[10 + d] = (_Float16)2.f * al[d];
    }
    rowA[15] = nh;  rowA[16] = nl;  rowA[17] = (_Float16)1.f; rowA[18] = (_Float16)1.f;
    rowB[15] = (_Float16)-1.f; rowB[16] = (_Float16)-1.f; rowB[17] = -nh; rowB[18] = -nl;

    half8* oA = (half8*)(distA + (size_t)idx * ROWH);
    half8* oB = (half8*)(distB + (size_t)idx * ROWH);
    #pragma unroll
    for (int q = 0; q < 4; ++q) {
      oA[q] = ((half8*)rowA)[q];
      oB[q] = ((half8*)rowB)[q];
    }
  }

  // ---- seg resize via LDS slab ----
  __shared__ float slab[10][128];
  int r0 = 8 * oyg - 1;                    // first input row of the slab (may be -1)
  float wy[4], wx[4]; int ty[4], tx[4];
  resize_w(oy, wy, ty);                    // weights (ty unused: rel index = 2*oyl+ay)
  resize_w(ox, wx, tx);

  half8 rs[4];
  #pragma unroll
  for (int q = 0; q < 4; ++q) rs[q] = (half8)(_Float16)0.f;

  const float* sb = segs + (size_t)n * NK * 128 * 128;
  #pragma unroll
  for (int k = 0; k < NK; ++k) {
    __syncthreads();                       // previous k's slab reads done
    const float* sk = sb + (size_t)k * 128 * 128;
    #pragma unroll
    for (int q = 0; q < 5; ++q) {          // 1280 floats, coalesced
      int e = threadIdx.x + q * 256;
      int rr = e >> 7, cc = e & 127;
      int row = r0 + rr;
      row = row < 0 ? 0 : (row > 127 ? 127 : row);  // clamp; invalid taps have weight 0
      slab[rr][cc] = sk[row * 128 + cc];
    }
    __syncthreads();
    float a = 0.f;
    #pragma unroll
    for (int ay = 0; ay < 4; ++ay) {
      int rel = 2 * oyl + ay;              // tap row - r0
      float rsum = 0.f;
      #pragma unroll
      for (int ax = 0; ax < 4; ++ax) rsum = fmaf(wx[ax], slab[rel][tx[ax]], rsum);
      a = fmaf(wy[ay], rsum, a);
    }
    rs[k >> 3][k & 7] = (_Float16)a;       // static index (loop fully unrolled)
  }

  half8* oS = (half8*)(segh + (size_t)idx * ROWH);
  #pragma unroll
  for (int q = 0; q < 4; ++q) oS[q] = rs[q];
}

// Triangular (symmetric) tile sweep. Wave item = (n, ist, c): 4 i-tiles x 16 j-tiles.
// S_full = 2*sum_{jt>it} T + sum_{jt==it} T;  T symmetric.
__global__ void __launch_bounds__(256) crf_mfma(const _Float16* __restrict__ distA,
                                                const _Float16* __restrict__ distB,
                                                const _Float16* __restrict__ segh,
                                                double* __restrict__ acc) {
  int lane = threadIdx.x & 63, wid = threadIdx.x >> 6;
  int item = blockIdx.x * 4 + wid;         // 0..4351
  int n = item / ITEMS_PER_IMG;
  int rem = item - n * ITEMS_PER_IMG;
  int g = 0;                               // g = ist>>2 (diag chunk index)
  for (;;) { int cnt = 4 * (16 - g); if (rem < cnt) break; rem -= cnt; ++g; }
  int span = 16 - g;
  int ist = 4 * g + rem / span;            // i-supertile (4 tiles = 64 rows)
  int c   = g + rem % span;                // j-chunk (16 tiles = 256 rows)

  int r = lane & 15, g4 = lane >> 4;
  const _Float16* dA = distA + (size_t)n * NP * ROWH;
  const _Float16* dB = distB + (size_t)n * NP * ROWH;
  const _Float16* sg = segh  + (size_t)n * NP * ROWH;

  half8 Ad[4], As[4];
  #pragma unroll
  for (int m = 0; m < 4; ++m) {
    size_t aoff = (size_t)((ist * 4 + m) * 16 + r) * ROWH + g4 * 8;
    Ad[m] = *(const half8*)(dA + aoff);
    As[m] = *(const half8*)(sg + aoff);
  }

  size_t boff = (size_t)(c * 256 + r) * ROWH + g4 * 8;
  const _Float16* pBd = dB + boff;
  const _Float16* pBs = sg + boff;

  float sum = 0.f;
  f32x4 zero = {0.f, 0.f, 0.f, 0.f};

  if (c > g) {                             // pure off-diagonal chunk: weight 2 for all
    float s2 = 0.f;
    #pragma unroll 2
    for (int jt = 0; jt < 16; ++jt) {
      half8 Bd = *(const half8*)pBd;
      half8 Bs = *(const half8*)pBs;
      pBd += 16 * ROWH; pBs += 16 * ROWH;
      #pragma unroll
      for (int m = 0; m < 4; ++m) {
        f32x4 ad = __builtin_amdgcn_mfma_f32_16x16x32_f16(Ad[m], Bd, zero, 0, 0, 0);
        f32x4 as_ = __builtin_amdgcn_mfma_f32_16x16x32_f16(As[m], Bs, zero, 0, 0, 0);
        #pragma unroll
        for (int q = 0; q < 4; ++q)
          s2 = fmaf(__builtin_amdgcn_exp2f(ad[q]), as_[q], s2);
      }
    }
    sum = 2.f * s2;
  } else {                                 // diagonal chunk: per-tile weight {0,1,2}
    #pragma unroll 2
    for (int jt = 0; jt < 16; ++jt) {
      int jta = c * 16 + jt;
      half8 Bd = *(const half8*)pBd;
      half8 Bs = *(const half8*)pBs;
      pBd += 16 * ROWH; pBs += 16 * ROWH;
      #pragma unroll
      for (int m = 0; m < 4; ++m) {
        int it = ist * 4 + m;
        float s = (jta > it) ? 2.f : (jta == it ? 1.f : 0.f);
        f32x4 ad = __builtin_amdgcn_mfma_f32_16x16x32_f16(Ad[m], Bd, zero, 0, 0, 0);
        f32x4 as_ = __builtin_amdgcn_mfma_f32_16x16x32_f16(As[m], Bs, zero, 0, 0, 0);
        #pragma unroll
        for (int q = 0; q < 4; ++q)
          sum = fmaf(__builtin_amdgcn_exp2f(ad[q]) * s, as_[q], sum);
      }
    }
  }

  // block reduction: wave shuffle then cross-wave via LDS
  #pragma unroll
  for (int off = 32; off > 0; off >>= 1) sum += __shfl_down(sum, off);
  __shared__ float red[4];
  if ((threadIdx.x & 63) == 0) red[wid] = sum;
  __syncthreads();
  if (threadIdx.x == 0) {
    float b = red[0] + red[1] + red[2] + red[3];
    atomicAdd(acc, (double)b);
  }
}

__global__ void finish_kernel(const double* __restrict__ acc, float* __restrict__ out) {
  // loss = -sum/N ; out = WEIGHT * loss = -1e-8/8 * sum
  out[0] = (float)(acc[0] * (-1e-8 / 8.0));
}

extern "C" void kernel_launch(void* const* d_in, const int* in_sizes, int n_in,
                              void* d_out, int out_size, void* d_ws, size_t ws_size,
                              hipStream_t stream) {
  const float* images = (const float*)d_in[0];   // [8,3,64,64]
  const float* segs   = (const float*)d_in[1];   // [8,21,128,128]
  float* out  = (float*)d_out;
  double* acc = (double*)d_ws;
  _Float16* distA = (_Float16*)((char*)d_ws + 256);              // 2 MB
  _Float16* distB = distA + (size_t)NIMG * NP * ROWH;            // 2 MB
  _Float16* segh  = distB + (size_t)NIMG * NP * ROWH;            // 2 MB

  hipMemsetAsync(d_ws, 0, 256, stream);          // zero the accumulator every call
  hipLaunchKernelGGL(prep_kernel, dim3(NIMG * 16), dim3(256), 0, stream,
                     images, segs, distA, distB, segh);
  hipLaunchKernelGGL(crf_mfma, dim3(NIMG * ITEMS_PER_IMG / 4), dim3(256), 0, stream,
                     distA, distB, segh, acc);
  hipLaunchKernelGGL(finish_kernel, dim3(1), dim3(1), 0, stream, acc, out);
}